// Round 1
// baseline (387.913 us; speedup 1.0000x reference)
//
#include <hip/hip_runtime.h>
#include <hip/hip_bf16.h>

#define N 224
#define TS 32
#define NT 7          // N / TS
#define PITCH 33      // 33 % 32 == 1 -> conflict-free column access

// Kernel 1: compute the 8 combined coefficients from theta into d_ws.
// out = (1-BETA)*x + (BETA/w_sum) * sum_g w[g] * x[sigma_g]
// coef[g] = (BETA/w_sum)*w[g];  coef[0] += (1-BETA)
__global__ void popmi_coeff_kernel(const float* __restrict__ theta,
                                   float* __restrict__ coef) {
    if (threadIdx.x == 0) {
        float m = theta[0];
        #pragma unroll
        for (int i = 1; i < 8; ++i) m = fmaxf(m, theta[i]);
        float e[8];
        float S = 0.f;
        #pragma unroll
        for (int i = 0; i < 8; ++i) { e[i] = expf(theta[i] - m); S += e[i]; }
        float w[8];
        float ws = 0.f;
        #pragma unroll
        for (int i = 0; i < 8; ++i) { w[i] = e[i] / S; ws += w[i]; }
        const float s = 0.5f / fmaxf(ws, 1e-12f);   // BETA / w_sum
        #pragma unroll
        for (int i = 0; i < 8; ++i) coef[i] = s * w[i];
        coef[0] += 0.5f;                            // + (1 - BETA)
    }
}

// Kernel 2: one 32x32 output tile per 256-thread block.
// Loads the 8 D4-related source tiles (all row-contiguous in global) into
// LDS, then combines with the precomputed coefficients.
__global__ __launch_bounds__(256) void popmi_main_kernel(
        const float* __restrict__ x, const float* __restrict__ coef,
        float* __restrict__ out) {
    __shared__ float lds[8][TS * PITCH];

    const int bid = blockIdx.x;
    const int p   = bid / (NT * NT);          // plane index (b*C + c)
    const int t   = bid % (NT * NT);
    const int I   = t / NT;
    const int J   = t % NT;
    const int i0  = I * TS, j0 = J * TS;
    const int ri0 = N - TS - i0;              // reversed-row tile base
    const int rj0 = N - TS - j0;

    const float* plane = x + (size_t)p * (N * N);

    // source tile origins (row, col) for g = 0..7
    const int r0[8] = { i0,  j0,  ri0, rj0, i0,  j0, ri0, rj0 };
    const int c0[8] = { j0,  ri0, rj0, i0,  rj0, i0, j0,  ri0 };

    const int tid = threadIdx.x;
    const int row = tid >> 3;           // 0..31
    const int cg  = (tid & 7) << 2;     // 0,4,...,28

    // broadcast coefficients (L2-cached, tiny)
    float c[8];
    #pragma unroll
    for (int g = 0; g < 8; ++g) c[g] = coef[g];

    // stage the 8 source tiles: float4 per thread per tile, all 128B-aligned
    #pragma unroll
    for (int u = 0; u < 8; ++u) {
        const float4 v = *reinterpret_cast<const float4*>(
            plane + (size_t)(r0[u] + row) * N + c0[u] + cg);
        float* dst = &lds[u][row * PITCH + cg];
        dst[0] = v.x; dst[1] = v.y; dst[2] = v.z; dst[3] = v.w;
    }
    __syncthreads();

    float res[4];
    #pragma unroll
    for (int q = 0; q < 4; ++q) {
        const int ti = row, tj = cg + q;
        const int rti = TS - 1 - ti, rtj = TS - 1 - tj;
        const float a0 = lds[0][ti  * PITCH + tj ];
        const float a1 = lds[1][tj  * PITCH + rti];
        const float a2 = lds[2][rti * PITCH + rtj];
        const float a3 = lds[3][rtj * PITCH + ti ];
        const float a4 = lds[4][ti  * PITCH + rtj];
        const float a5 = lds[5][tj  * PITCH + ti ];
        const float a6 = lds[6][rti * PITCH + tj ];
        const float a7 = lds[7][rtj * PITCH + rti];
        res[q] = c[0]*a0 + c[1]*a1 + c[2]*a2 + c[3]*a3
               + c[4]*a4 + c[5]*a5 + c[6]*a6 + c[7]*a7;
    }

    *reinterpret_cast<float4*>(out + (size_t)p * (N * N)
                               + (size_t)(i0 + row) * N + j0 + cg)
        = make_float4(res[0], res[1], res[2], res[3]);
}

extern "C" void kernel_launch(void* const* d_in, const int* in_sizes, int n_in,
                              void* d_out, int out_size, void* d_ws, size_t ws_size,
                              hipStream_t stream) {
    const float* x     = (const float*)d_in[0];
    const float* theta = (const float*)d_in[1];
    float* out  = (float*)d_out;
    float* coef = (float*)d_ws;

    const int planes = in_sizes[0] / (N * N);   // 16*192 = 3072
    popmi_coeff_kernel<<<1, 64, 0, stream>>>(theta, coef);
    popmi_main_kernel<<<planes * NT * NT, 256, 0, stream>>>(x, coef, out);
}

// Round 2
// 261.510 us; speedup vs baseline: 1.4834x; 1.4834x over previous
//
#include <hip/hip_runtime.h>
#include <hip/hip_bf16.h>

#define N 224
#define TS 32
#define NT 7          // N / TS
#define PITCH 33      // 33 % 32 == 1 -> conflict-free row AND column access

// Kernel 1: compute the 8 combined coefficients from theta into d_ws.
// out = (1-BETA)*x + (BETA/w_sum) * sum_g w[g] * x[sigma_g]
// coef[g] = (BETA/w_sum)*w[g];  coef[0] += (1-BETA)
__global__ void popmi_coeff_kernel(const float* __restrict__ theta,
                                   float* __restrict__ coef) {
    if (threadIdx.x == 0) {
        float m = theta[0];
        #pragma unroll
        for (int i = 1; i < 8; ++i) m = fmaxf(m, theta[i]);
        float e[8];
        float S = 0.f;
        #pragma unroll
        for (int i = 0; i < 8; ++i) { e[i] = expf(theta[i] - m); S += e[i]; }
        float w[8];
        float ws = 0.f;
        #pragma unroll
        for (int i = 0; i < 8; ++i) { w[i] = e[i] / S; ws += w[i]; }
        const float s = 0.5f / fmaxf(ws, 1e-12f);   // BETA / w_sum
        #pragma unroll
        for (int i = 0; i < 8; ++i) coef[i] = s * w[i];
        coef[0] += 0.5f;                            // + (1 - BETA)
    }
}

// Kernel 2: D4-orbit blocking. One block per (plane, orbit). The 8 source
// tiles needed by ANY output tile in an orbit are exactly the orbit's tiles,
// so we stage them once and emit up to 8 output tiles -> every input byte is
// read from HBM by exactly one block (exact-once fetch, cache-independent).
//
// Group element g maps output pixel (i,j) -> source pixel m_g(i,j):
//   m0:(i,j) m1:(j,ri) m2:(ri,rj) m3:(rj,i) m4:(i,rj) m5:(j,i) m6:(ri,j) m7:(rj,ri)
// The same maps act on tile coords (r at NT scale) and intra-tile coords
// (r at TS scale). comp[g][h] = index of m_g∘m_h (signed-permutation algebra).
__global__ __launch_bounds__(256, 4) void popmi_orbit_kernel(
        const float* __restrict__ x, const float* __restrict__ coef,
        float* __restrict__ out) {
    __shared__ float lds[8][TS * PITCH];

    const int bid = blockIdx.x;
    const int p   = bid / 10;           // plane index (b*C + c)
    const int o   = bid - p * 10;       // orbit id 0..9

    // 10 orbits of the 7x7 tile grid under D4:
    //  0-2: generic (size 8), 3-5: axis j=3 (size 4), 6-8: diagonal (size 4),
    //  9: center (size 1). H = {0..nH-1} gives each tile exactly once.
    const int OI[10]  = {0,0,1, 0,1,2, 0,1,2, 3};
    const int OJ[10]  = {1,2,2, 3,3,3, 0,1,2, 3};
    const int ONH[10] = {8,8,8, 4,4,4, 4,4,4, 1};

    const int I = OI[o], J = OJ[o], nH = ONH[o];
    const int rI = NT - 1 - I, rJ = NT - 1 - J;

    // tile location tau_u(t) for u = 0..7 (duplicates for degenerate orbits)
    const int TI[8] = { I,  J, rI, rJ,  I,  J, rI, rJ };
    const int TJ[8] = { J, rI, rJ,  I, rJ,  I,  J, rI };

    const float* plane  = x   + (size_t)p * (N * N);
    float*       oplane = out + (size_t)p * (N * N);

    const int tid = threadIdx.x;
    const int row = tid >> 3;           // 0..31
    const int cg  = (tid & 7) << 2;     // 0,4,...,28

    float c[8];
    #pragma unroll
    for (int g = 0; g < 8; ++g) c[g] = coef[g];

    // stage the orbit tiles (row-contiguous float4 global loads)
    #pragma unroll
    for (int u = 0; u < 8; ++u) {
        const float4 v = *reinterpret_cast<const float4*>(
            plane + (size_t)(TI[u] * TS + row) * N + TJ[u] * TS + cg);
        float* dst = &lds[u][row * PITCH + cg];
        dst[0] = v.x; dst[1] = v.y; dst[2] = v.z; dst[3] = v.w;
    }
    __syncthreads();

    // comp[g][h] = index of m_g ∘ m_h
    const int comp[8][8] = {
        {0,1,2,3,4,5,6,7},
        {1,2,3,0,7,4,5,6},
        {2,3,0,1,6,7,4,5},
        {3,0,1,2,5,6,7,4},
        {4,5,6,7,0,1,2,3},
        {5,6,7,4,3,0,1,2},
        {6,7,4,5,2,3,0,1},
        {7,4,5,6,1,2,3,0},
    };

    const int ti  = row;
    const int rti = TS - 1 - ti;

    #pragma unroll
    for (int h = 0; h < 8; ++h) {
        if (h < nH) {                   // wave-uniform guard
            float res[4];
            #pragma unroll
            for (int q = 0; q < 4; ++q) {
                const int tj  = cg + q;
                const int rtj = TS - 1 - tj;
                res[q] =
                    c[0] * lds[comp[0][h]][ti  * PITCH + tj ] +
                    c[1] * lds[comp[1][h]][tj  * PITCH + rti] +
                    c[2] * lds[comp[2][h]][rti * PITCH + rtj] +
                    c[3] * lds[comp[3][h]][rtj * PITCH + ti ] +
                    c[4] * lds[comp[4][h]][ti  * PITCH + rtj] +
                    c[5] * lds[comp[5][h]][tj  * PITCH + ti ] +
                    c[6] * lds[comp[6][h]][rti * PITCH + tj ] +
                    c[7] * lds[comp[7][h]][rtj * PITCH + rti];
            }
            // output tile location = tau_h(t)
            *reinterpret_cast<float4*>(
                oplane + (size_t)(TI[h] * TS + row) * N + TJ[h] * TS + cg)
                = make_float4(res[0], res[1], res[2], res[3]);
        }
    }
}

extern "C" void kernel_launch(void* const* d_in, const int* in_sizes, int n_in,
                              void* d_out, int out_size, void* d_ws, size_t ws_size,
                              hipStream_t stream) {
    const float* x     = (const float*)d_in[0];
    const float* theta = (const float*)d_in[1];
    float* out  = (float*)d_out;
    float* coef = (float*)d_ws;

    const int planes = in_sizes[0] / (N * N);   // 16*192 = 3072
    popmi_coeff_kernel<<<1, 64, 0, stream>>>(theta, coef);
    popmi_orbit_kernel<<<planes * 10, 256, 0, stream>>>(x, coef, out);
}

// Round 3
// 236.599 us; speedup vs baseline: 1.6395x; 1.1053x over previous
//
#include <hip/hip_runtime.h>
#include <hip/hip_bf16.h>

#define N 224
#define TS 32
#define NT 7          // N / TS
#define PITCH 33      // 33 % 32 == 1 -> conflict-free row AND column access

// Group element g maps output pixel (i,j) -> source pixel m_g(i,j):
//   m0:(i,j) m1:(j,ri) m2:(ri,rj) m3:(rj,i) m4:(i,rj) m5:(j,i) m6:(ri,j) m7:(rj,ri)
// COMP[g][h] = index of m_g ∘ m_h (verified: passed in rounds 1-2).
constexpr int COMP[8][8] = {
    {0,1,2,3,4,5,6,7},
    {1,2,3,0,7,4,5,6},
    {2,3,0,1,6,7,4,5},
    {3,0,1,2,5,6,7,4},
    {4,5,6,7,0,1,2,3},
    {5,6,7,4,3,0,1,2},
    {6,7,4,5,2,3,0,1},
    {7,4,5,6,1,2,3,0},
};
// CAN[class][u] = canonical LDS slot of tau_u (degenerate orbits have
// coincident tiles: axis u4..7 -> {0,3,2,1}; diag u4..7 -> {1,0,3,2}).
constexpr int CAN[4][8] = {
    {0,1,2,3,4,5,6,7},   // class 0: generic (size 8)
    {0,1,2,3,0,3,2,1},   // class 1: axis J==3 (size 4)
    {0,1,2,3,1,0,3,2},   // class 2: diagonal I==J (size 4)
    {0,0,0,0,0,0,0,0},   // class 3: center (size 1)
};

// One D4 orbit of 32x32 tiles: stage the NU unique tiles once, emit NH
// output tiles. Everything constant-folds per template instantiation.
template<int C, int NH, int NU>
__device__ __forceinline__ void orbit_compute(
        const float* __restrict__ plane, float* __restrict__ oplane,
        const float* c, float (*lds)[TS * PITCH],
        int I, int J, int row, int cg)
{
    const int rI = NT - 1 - I, rJ = NT - 1 - J;
    const int TI[8] = { I,  J, rI, rJ,  I,  J, rI, rJ };
    const int TJ[8] = { J, rI, rJ,  I, rJ,  I,  J, rI };

    #pragma unroll
    for (int u = 0; u < NU; ++u) {
        const float4 v = *reinterpret_cast<const float4*>(
            plane + (size_t)(TI[u] * TS + row) * N + TJ[u] * TS + cg);
        float* dst = &lds[u][row * PITCH + cg];
        dst[0] = v.x; dst[1] = v.y; dst[2] = v.z; dst[3] = v.w;
    }
    __syncthreads();

    const int ti = row, rti = TS - 1 - row;
    #pragma unroll
    for (int h = 0; h < NH; ++h) {
        float res[4];
        #pragma unroll
        for (int q = 0; q < 4; ++q) {
            const int tj = cg + q, rtj = TS - 1 - tj;
            res[q] =
                c[0] * lds[CAN[C][COMP[0][h]]][ti  * PITCH + tj ] +
                c[1] * lds[CAN[C][COMP[1][h]]][tj  * PITCH + rti] +
                c[2] * lds[CAN[C][COMP[2][h]]][rti * PITCH + rtj] +
                c[3] * lds[CAN[C][COMP[3][h]]][rtj * PITCH + ti ] +
                c[4] * lds[CAN[C][COMP[4][h]]][ti  * PITCH + rtj] +
                c[5] * lds[CAN[C][COMP[5][h]]][tj  * PITCH + ti ] +
                c[6] * lds[CAN[C][COMP[6][h]]][rti * PITCH + tj ] +
                c[7] * lds[CAN[C][COMP[7][h]]][rtj * PITCH + rti];
        }
        *reinterpret_cast<float4*>(
            oplane + (size_t)(TI[h] * TS + row) * N + TJ[h] * TS + cg)
            = make_float4(res[0], res[1], res[2], res[3]);
    }
}

__global__ __launch_bounds__(256, 4) void popmi_kernel(
        const float* __restrict__ x, const float* __restrict__ theta,
        float* __restrict__ out)
{
    __shared__ float lds[8][TS * PITCH];

    // coefficients from theta, recomputed per thread (8 floats; trivial,
    // deterministic): coef[g] = (BETA/w_sum)*softmax(theta)[g]; coef0 += 1-BETA
    float th[8];
    #pragma unroll
    for (int i = 0; i < 8; ++i) th[i] = theta[i];
    float m = th[0];
    #pragma unroll
    for (int i = 1; i < 8; ++i) m = fmaxf(m, th[i]);
    float e[8], S = 0.f;
    #pragma unroll
    for (int i = 0; i < 8; ++i) { e[i] = expf(th[i] - m); S += e[i]; }
    float w[8], ws = 0.f;
    #pragma unroll
    for (int i = 0; i < 8; ++i) { w[i] = e[i] / S; ws += w[i]; }
    const float s = 0.5f / fmaxf(ws, 1e-12f);
    float c[8];
    #pragma unroll
    for (int i = 0; i < 8; ++i) c[i] = s * w[i];
    c[0] += 0.5f;

    const int bid = blockIdx.x;
    const int p   = bid / 10;           // plane
    const int o   = bid - p * 10;       // orbit id 0..9

    // orbit rep (I,J), packed 3 bits/entry (avoid runtime-indexed local array)
    // OI = {0,0,1, 0,1,2, 0,1,2, 3}, OJ = {1,2,2, 3,3,3, 0,1,2, 3}
    const int I = (0x1A211040u >> (3 * o)) & 7;
    const int J = (0x1A21B691u >> (3 * o)) & 7;

    const float* plane  = x   + (size_t)p * (N * N);
    float*       oplane = out + (size_t)p * (N * N);

    const int tid = threadIdx.x;
    const int row = tid >> 3;           // 0..31
    const int cg  = (tid & 7) << 2;     // 0,4,...,28

    if (o < 3)      orbit_compute<0,8,8>(plane, oplane, c, lds, I, J, row, cg);
    else if (o < 6) orbit_compute<1,4,4>(plane, oplane, c, lds, I, J, row, cg);
    else if (o < 9) orbit_compute<2,4,4>(plane, oplane, c, lds, I, J, row, cg);
    else            orbit_compute<3,1,1>(plane, oplane, c, lds, I, J, row, cg);
}

extern "C" void kernel_launch(void* const* d_in, const int* in_sizes, int n_in,
                              void* d_out, int out_size, void* d_ws, size_t ws_size,
                              hipStream_t stream) {
    const float* x     = (const float*)d_in[0];
    const float* theta = (const float*)d_in[1];
    float* out = (float*)d_out;

    const int planes = in_sizes[0] / (N * N);   // 16*192 = 3072
    popmi_kernel<<<planes * 10, 256, 0, stream>>>(x, theta, out);
}